// Round 1
// baseline (4281.078 us; speedup 1.0000x reference)
//
#include <hip/hip_runtime.h>
#include <hip/hip_bf16.h>
#include <cstdint>

// MoE top-2, T=4096 D=2048 H=5632 E=8.
// Strategy: f32 gate (selection-exact) + bf16 MFMA grouped GEMMs on padded
// per-expert slot lists. Weights repacked f32->bf16 transposed ([n][k]) each
// call so GEMM staging uses global_load_lds width=16 + ds_read_b128 (m97
// structure). Gate weight folded into h so the down-proj GEMM is pure, then
// scatter-add (atomicAdd f32) into d_out preloaded with next_r.
// Workspace budget ~779 MB.

#define T_TOK 4096
#define DDIM  2048
#define HDIM  5632
#define NEXP  8
#define NSLOT 9216   // 2*T + 8*127 padding worst case, rounded up

typedef __attribute__((ext_vector_type(8))) short          short8;
typedef __attribute__((ext_vector_type(8))) unsigned short ushort8;
typedef __attribute__((ext_vector_type(4))) unsigned short ushort4v;
typedef __attribute__((ext_vector_type(4))) float          f32x4;

__device__ __forceinline__ unsigned short f2bf(float f) {
  __bf16 h = (__bf16)f;
  return __builtin_bit_cast(unsigned short, h);
}
__device__ __forceinline__ float bf2f(unsigned short u) {
  unsigned int i = ((unsigned int)u) << 16;
  return __builtin_bit_cast(float, i);
}

#define GLD16(g, s) __builtin_amdgcn_global_load_lds( \
    (const __attribute__((address_space(1))) void*)(g), \
    (__attribute__((address_space(3))) void*)(s), 16, 0, 0)

// ---------------- init: zero routing arrays ----------------
__global__ void k_init(float* __restrict__ gate_slot, int* __restrict__ ids,
                       int* __restrict__ counts_fill) {
  int i = blockIdx.x * 256 + threadIdx.x;
  if (i < NSLOT) { gate_slot[i] = 0.f; ids[i] = 0; }
  if (i < 16) counts_fill[i] = 0;
}

// ---------------- x: f32 -> bf16 ----------------
__global__ void k_convert_x(const float* __restrict__ x, unsigned short* __restrict__ xb) {
  int i = (blockIdx.x * 256 + threadIdx.x) * 8;
  float4 a = *(const float4*)(x + i);
  float4 b = *(const float4*)(x + i + 4);
  ushort8 o;
  o[0]=f2bf(a.x); o[1]=f2bf(a.y); o[2]=f2bf(a.z); o[3]=f2bf(a.w);
  o[4]=f2bf(b.x); o[5]=f2bf(b.y); o[6]=f2bf(b.z); o[7]=f2bf(b.w);
  *(ushort8*)(xb + i) = o;
}

// ---------------- weight repack: f32 [R][C] -> bf16 [C][R], per expert (z) ----------------
__global__ void k_transpose(const float* __restrict__ in, unsigned short* __restrict__ out,
                            int R, int C) {
  __shared__ __align__(16) unsigned short tile[64][72];  // [r][c], pad to 72
  size_t esz = (size_t)R * C;
  in  += (size_t)blockIdx.z * esz;
  out += (size_t)blockIdx.z * esz;
  int c0 = blockIdx.x * 64, r0 = blockIdx.y * 64;
  int t = threadIdx.x;
  int rr = t >> 4;           // 0..15
  int c4 = (t & 15) * 4;     // 0..60
#pragma unroll
  for (int i = 0; i < 4; i++) {
    int r = rr + i * 16;
    float4 v = *(const float4*)(in + (size_t)(r0 + r) * C + c0 + c4);
    ushort4v w; w[0]=f2bf(v.x); w[1]=f2bf(v.y); w[2]=f2bf(v.z); w[3]=f2bf(v.w);
    *(ushort4v*)&tile[r][c4] = w;
  }
  __syncthreads();
  int q = t & 7;             // 8-elem chunk along r
  int cbase = t >> 3;        // 0..31
#pragma unroll
  for (int i = 0; i < 2; i++) {
    int c = cbase + i * 32;
    ushort8 o;
#pragma unroll
    for (int j = 0; j < 8; j++) o[j] = tile[q * 8 + j][c];
    *(ushort8*)(out + (size_t)(c0 + c) * R + r0 + q * 8) = o;
  }
}

// ---------------- gate: f32 logits, top-2, softmax ----------------
__global__ void k_gate(const float* __restrict__ x, const float* __restrict__ Wg,
                       int2* __restrict__ meta_e, float2* __restrict__ meta_w,
                       int* __restrict__ counts) {
  int lane = threadIdx.x & 63;
  int t = blockIdx.x * 4 + (threadIdx.x >> 6);
  float acc[8] = {0,0,0,0,0,0,0,0};
  const float* xr = x + (size_t)t * DDIM;
  for (int d = lane; d < DDIM; d += 64) {
    float xv = xr[d];
    const float4* wg = (const float4*)(Wg + d * 8);
    float4 w0 = wg[0], w1 = wg[1];
    acc[0] += xv*w0.x; acc[1] += xv*w0.y; acc[2] += xv*w0.z; acc[3] += xv*w0.w;
    acc[4] += xv*w1.x; acc[5] += xv*w1.y; acc[6] += xv*w1.z; acc[7] += xv*w1.w;
  }
#pragma unroll
  for (int m = 32; m >= 1; m >>= 1) {
#pragma unroll
    for (int e = 0; e < 8; e++) acc[e] += __shfl_xor(acc[e], m);
  }
  if (lane == 0) {
    int e0 = 0; float l0 = acc[0];
#pragma unroll
    for (int e = 1; e < 8; e++) if (acc[e] > l0) { l0 = acc[e]; e0 = e; }
    int e1 = -1; float l1 = -3.4e38f;
#pragma unroll
    for (int e = 0; e < 8; e++) if (e != e0 && acc[e] > l1) { l1 = acc[e]; e1 = e; }
    float z = __expf(l1 - l0);        // l1 <= l0, z in (0,1]
    float inv = 1.f / (1.f + z);
    meta_e[t] = make_int2(e0, e1);
    meta_w[t] = make_float2(inv, z * inv);
    atomicAdd(&counts[e0], 1);
    atomicAdd(&counts[e1], 1);
  }
}

// ---------------- scan: padded expert offsets ----------------
__global__ void k_scan(const int* __restrict__ counts, int* __restrict__ offp) {
  if (threadIdx.x == 0) {
    int off = 0; offp[0] = 0;
    for (int e = 0; e < NEXP; e++) {
      int cap = (counts[e] + 127) & ~127;
      off += cap; offp[e + 1] = off;
    }
  }
}

// ---------------- scatter tokens into slots ----------------
__global__ void k_scatter(const int2* __restrict__ meta_e, const float2* __restrict__ meta_w,
                          const int* __restrict__ offp, int* __restrict__ fill,
                          int* __restrict__ ids, float* __restrict__ gate_slot) {
  int t = blockIdx.x * 256 + threadIdx.x;
  if (t >= T_TOK) return;
  int2 ee = meta_e[t]; float2 ww = meta_w[t];
  int p0 = atomicAdd(&fill[ee.x], 1);
  int s0 = offp[ee.x] + p0;
  ids[s0] = t; gate_slot[s0] = ww.x;
  int p1 = atomicAdd(&fill[ee.y], 1);
  int s1 = offp[ee.y] + p1;
  ids[s1] = t; gate_slot[s1] = ww.y;
}

// ---------------- grouped GEMM, m97 structure ----------------
// G1=true : A = xb gathered via ids (K=2048), B = w1t/w3t [E][5632][2048], out bf16 h [NSLOT][5632]
// G1=false: A = h rows direct      (K=5632), B = w2t      [E][2048][5632], atomicAdd f32 into out[token]
template<bool G1>
__global__ __launch_bounds__(256) void k_gemm(
    const unsigned short* __restrict__ Abase, const int* __restrict__ ids,
    const int* __restrict__ offp, const unsigned short* __restrict__ Bbase,
    void* __restrict__ outp) {
  constexpr int KD = G1 ? DDIM : HDIM;
  constexpr int NT = G1 ? HDIM : DDIM;
  int e = blockIdx.x >> 5, rt = blockIdx.x & 31;
  int sbeg = offp[e], cap = offp[e + 1] - sbeg;
  if (rt * 128 >= cap) return;          // block-uniform early exit
  int s0 = sbeg + rt * 128;
  int n0 = blockIdx.y * 128;
  __shared__ __align__(16) unsigned short As[128 * 32];
  __shared__ __align__(16) unsigned short Bs[128 * 32];
  int tid = threadIdx.x, w = tid >> 6, lane = tid & 63;

  // staging: wave w loads rows [w*32, w*32+32) of both tiles, 16 rows per glld
  int ar0 = w * 32 + (lane >> 2);
  int ar1 = ar0 + 16;
  int kc  = (lane & 3) * 8;             // bf16 elems within BK=32
  const unsigned short *gA0, *gA1;
  if (G1) {
    gA0 = Abase + (size_t)ids[s0 + ar0] * KD + kc;
    gA1 = Abase + (size_t)ids[s0 + ar1] * KD + kc;
  } else {
    gA0 = Abase + (size_t)(s0 + ar0) * KD + kc;
    gA1 = Abase + (size_t)(s0 + ar1) * KD + kc;
  }
  const unsigned short* gB0 = Bbase + ((size_t)e * NT + n0 + ar0) * KD + kc;
  const unsigned short* gB1 = Bbase + ((size_t)e * NT + n0 + ar1) * KD + kc;
  unsigned short* lA0 = As + (w * 32     ) * 32;  // wave-uniform LDS bases
  unsigned short* lA1 = As + (w * 32 + 16) * 32;
  unsigned short* lB0 = Bs + (w * 32     ) * 32;
  unsigned short* lB1 = Bs + (w * 32 + 16) * 32;

  int wm = (w & 1) * 64, wn = (w >> 1) * 64;
  f32x4 acc[4][4] = {};
  int mrow = lane & 15, q8 = (lane >> 4) * 8;

#pragma unroll 1
  for (int kk = 0; kk < KD; kk += 32) {
    __syncthreads();                    // prev iter ds_reads done before overwrite
    GLD16(gA0 + kk, lA0);
    GLD16(gA1 + kk, lA1);
    GLD16(gB0 + kk, lB0);
    GLD16(gB1 + kk, lB1);
    __syncthreads();                    // drains vmcnt: staging visible
    short8 af[4], bfv[4];
#pragma unroll
    for (int m = 0; m < 4; m++)
      af[m] = *(const short8*)(As + (wm + m * 16 + mrow) * 32 + q8);
#pragma unroll
    for (int n = 0; n < 4; n++)
      bfv[n] = *(const short8*)(Bs + (wn + n * 16 + mrow) * 32 + q8);
#pragma unroll
    for (int m = 0; m < 4; m++)
#pragma unroll
      for (int n = 0; n < 4; n++)
        acc[m][n] = __builtin_amdgcn_mfma_f32_16x16x32_bf16(af[m], bfv[n], acc[m][n], 0, 0, 0);
  }

  // epilogue: C/D layout col=lane&15, row=(lane>>4)*4+reg  [m89-verified]
  int qr = (lane >> 4) * 4, cl = lane & 15;
  if (G1) {
    unsigned short* Ho = (unsigned short*)outp;
#pragma unroll
    for (int m = 0; m < 4; m++) {
      int rbase = wm + m * 16 + qr;
#pragma unroll
      for (int n = 0; n < 4; n++) {
        int col = n0 + wn + n * 16 + cl;
#pragma unroll
        for (int i = 0; i < 4; i++)
          Ho[(size_t)(s0 + rbase + i) * HDIM + col] = f2bf(acc[m][n][i]);
      }
    }
  } else {
    float* Og = (float*)outp;
#pragma unroll
    for (int m = 0; m < 4; m++) {
      int rbase = wm + m * 16 + qr;
#pragma unroll
      for (int i = 0; i < 4; i++) {
        int tok = ids[s0 + rbase + i];
#pragma unroll
        for (int n = 0; n < 4; n++) {
          int col = n0 + wn + n * 16 + cl;
          atomicAdd(Og + (size_t)tok * DDIM + col, acc[m][n][i]);
        }
      }
    }
  }
}

// ---------------- fused swiglu * gate (in place into h1) ----------------
__global__ void k_swiglu(unsigned short* __restrict__ h1, const unsigned short* __restrict__ h3,
                         const float* __restrict__ gate_slot) {
  int idx = blockIdx.x * 256 + threadIdx.x;
  int s = idx / (HDIM / 8);             // 704 threads per slot row
  size_t i = (size_t)idx * 8;
  float g = gate_slot[s];
  ushort8 a = *(const ushort8*)(h1 + i);
  ushort8 b = *(const ushort8*)(h3 + i);
  ushort8 o;
#pragma unroll
  for (int j = 0; j < 8; j++) {
    float av = bf2f(a[j]), bv = bf2f(b[j]);
    float sv = av / (1.f + __expf(-av));
    o[j] = f2bf(g * sv * bv);
  }
  *(ushort8*)(h1 + i) = o;
}

extern "C" void kernel_launch(void* const* d_in, const int* in_sizes, int n_in,
                              void* d_out, int out_size, void* d_ws, size_t ws_size,
                              hipStream_t stream) {
  const float* x  = (const float*)d_in[0];
  const float* Wg = (const float*)d_in[1];
  const float* w1 = (const float*)d_in[2];
  const float* w2 = (const float*)d_in[3];   // note setup order: w1, w2, w3
  const float* w3 = (const float*)d_in[4];
  const float* nr = (const float*)d_in[5];
  char* ws = (char*)d_ws;

  const size_t SZ_XB = (size_t)T_TOK * DDIM * 2;        // 16,777,216
  const size_t SZ_W  = (size_t)NEXP * DDIM * HDIM * 2;  // 184,549,376
  const size_t SZ_H  = (size_t)NSLOT * HDIM * 2;        // 103,809,024
  unsigned short* xb  = (unsigned short*)(ws);
  unsigned short* w1t = (unsigned short*)(ws + SZ_XB);
  unsigned short* w3t = (unsigned short*)(ws + SZ_XB + SZ_W);
  unsigned short* w2t = (unsigned short*)(ws + SZ_XB + 2 * SZ_W);
  unsigned short* h1  = (unsigned short*)(ws + SZ_XB + 3 * SZ_W);
  unsigned short* h3  = (unsigned short*)(ws + SZ_XB + 3 * SZ_W + SZ_H);
  char* small = ws + SZ_XB + 3 * SZ_W + 2 * SZ_H;       // ~778.0 MB so far
  float*  gate_slot = (float*)small;                    // 36,864 B
  int*    ids       = (int*)(small + 36864);            // 36,864 B
  int2*   meta_e    = (int2*)(small + 73728);           // 32,768 B
  float2* meta_w    = (float2*)(small + 106496);        // 32,768 B
  int*    counts    = (int*)(small + 139264);           // counts[8] fill[8] offp[9]
  int*    fill      = counts + 8;
  int*    offp      = counts + 16;

  k_init<<<36, 256, 0, stream>>>(gate_slot, ids, counts);
  k_convert_x<<<4096, 256, 0, stream>>>(x, xb);
  k_transpose<<<dim3(88, 32, 8), 256, 0, stream>>>(w1, w1t, DDIM, HDIM);
  k_transpose<<<dim3(88, 32, 8), 256, 0, stream>>>(w3, w3t, DDIM, HDIM);
  k_transpose<<<dim3(32, 88, 8), 256, 0, stream>>>(w2, w2t, HDIM, DDIM);
  k_gate<<<1024, 256, 0, stream>>>(x, Wg, meta_e, meta_w, counts);
  k_scan<<<1, 64, 0, stream>>>(counts, offp);
  k_scatter<<<16, 256, 0, stream>>>(meta_e, meta_w, offp, fill, ids, gate_slot);
  k_gemm<true><<<dim3(256, 44), 256, 0, stream>>>(xb, ids, offp, w1t, h1);
  k_gemm<true><<<dim3(256, 44), 256, 0, stream>>>(xb, ids, offp, w3t, h3);
  k_swiglu<<<25344, 256, 0, stream>>>(h1, h3, gate_slot);
  hipMemcpyAsync(d_out, nr, (size_t)T_TOK * DDIM * 4, hipMemcpyDeviceToDevice, stream);
  k_gemm<false><<<dim3(256, 16), 256, 0, stream>>>(h1, ids, offp, w2t, d_out);
}